// Round 14
// baseline (1131.198 us; speedup 1.0000x reference)
//
#include <hip/hip_runtime.h>

#define N_ROWS 32768
#define C_DIM  512
#define K_CODES 1024
#define Q_STAGES 8

typedef __attribute__((ext_vector_type(8))) short bf16x8;      // 8 bf16 (4 VGPR)
typedef __attribute__((ext_vector_type(16))) float f32x16;     // 32x32 MFMA acc
typedef __attribute__((ext_vector_type(4))) unsigned short u16x4;
typedef __attribute__((ext_vector_type(8))) unsigned short u16x8;

// workspace layout (bytes) — total <= proven 69.37MB budget
#define ZEH_OFF 0ull          // [N][C] ushort (bf16 hi)  33,554,432
#define ZEL_OFF 33554432ull   // [N][C] ushort (bf16 lo)  33,554,432
#define CBH_OFF 67108864ull   // [K][C] ushort, current stage  1,048,576
#define CBL_OFF 68157440ull   // [K][C] ushort               1,048,576
#define C2_OFF  69206016ull   // [Q][K] float                    32,768
#define RPT_OFF 69238784ull   // [Q][256] float                   8,192

#define GLD(gp, lp) __builtin_amdgcn_global_load_lds( \
    (const __attribute__((address_space(1))) void*)(gp), \
    (__attribute__((address_space(3))) void*)(lp), 16, 0, 0)

__device__ __forceinline__ float bf_hi_f(float f) {
    return __uint_as_float(__float_as_uint(f) & 0xFFFF0000u);
}
__device__ __forceinline__ unsigned short bf_hi_u(float f) {
    return (unsigned short)(__float_as_uint(f) >> 16);
}
__device__ __forceinline__ float u2f(unsigned short u) {
    return __uint_as_float(((unsigned int)u) << 16);
}

// ---- split fp32 -> (hi, lo) bf16 pair, 4 elems/thread ----
__global__ __launch_bounds__(256) void split_kernel(
    const float* __restrict__ src, unsigned short* __restrict__ h,
    unsigned short* __restrict__ l, int n4)
{
    int i = blockIdx.x * 256 + threadIdx.x;
    if (i >= n4) return;
    float4 v = *(const float4*)(src + (size_t)i * 4);
    u16x4 hv, lv;
    float f, hf;
    f = v.x; hv[0] = bf_hi_u(f); hf = bf_hi_f(f); lv[0] = bf_hi_u(f - hf);
    f = v.y; hv[1] = bf_hi_u(f); hf = bf_hi_f(f); lv[1] = bf_hi_u(f - hf);
    f = v.z; hv[2] = bf_hi_u(f); hf = bf_hi_f(f); lv[2] = bf_hi_u(f - hf);
    f = v.w; hv[3] = bf_hi_u(f); hf = bf_hi_f(f); lv[3] = bf_hi_u(f - hf);
    *(u16x4*)(h + (size_t)i * 4) = hv;
    *(u16x4*)(l + (size_t)i * 4) = lv;
}

// ---- row sum-of-squares (codebook norms), one wave per 512-float row ----
__global__ __launch_bounds__(256) void rowsq_kernel(
    const float* __restrict__ src, float* __restrict__ dst, int nrows)
{
    int wave = (blockIdx.x * blockDim.x + threadIdx.x) >> 6;
    int lane = threadIdx.x & 63;
    if (wave >= nrows) return;
    const float* p = src + (size_t)wave * C_DIM + lane * 8;
    float4 a = *(const float4*)p;
    float4 b = *(const float4*)(p + 4);
    float s = a.x*a.x + a.y*a.y + a.z*a.z + a.w*a.w
            + b.x*b.x + b.y*b.y + b.z*b.z + b.w*b.w;
    #pragma unroll
    for (int off = 1; off < 64; off <<= 1) s += __shfl_xor(s, off);
    if (lane == 0) dst[wave] = s;
}

// ---- MFMA distance + argmin + FUSED residual update ----
// Main loop: R7 skeleton (triple-buffer, depth-2 prefetch, counted vmcnt(6),
// 1 barrier/iter) but with 32x32x16 bf16 MFMA (24 instrs/K-step vs 48;
// higher pipe throughput 2382 vs 2075 TF). 8 waves (2Mx4N), wave tile 64x64
// = 2x2 tiles of 32x32. C/D layout: col=lane&31, row=(reg&3)+8*(reg>>2)
// +4*(lane>>5) [HW-verified]. k-slot = kh*2+(lane>>5) (consistent A/B
// k-permutation leaves the dot invariant).
#define DBM2 128
#define DBNC 256
#define DBK 32
#define NSTEPS 64  // 4 chunks * 16 K-steps

__global__ __launch_bounds__(512, 2) void dist_fused_kernel(
    const int s, const float* __restrict__ x,
    unsigned short* __restrict__ zeh, unsigned short* __restrict__ zel,
    const unsigned short* __restrict__ cbh, const unsigned short* __restrict__ cbl,
    const float* __restrict__ c2s,
    float* __restrict__ out, float* __restrict__ rpart)
{
    __shared__ unsigned short sA[3][2][DBM2 * DBK];   // 48 KiB
    __shared__ unsigned short sB[3][2][DBNC * DBK];   // 96 KiB
    __shared__ float c2_lds[K_CODES];                 // 4 KiB
    __shared__ int   win[DBM2];                       // 512 B
    __shared__ float swsum[8];                        // 32 B

    const int tid  = threadIdx.x;
    const int lane = tid & 63;
    const int w    = tid >> 6;     // wave 0..7
    const int wr   = w >> 2;       // 0..1 (M)
    const int wc   = w & 3;        // 0..3 (N)
    const int r5   = lane & 31;    // frag row/col within 32
    const int ksl  = lane >> 5;    // k half-slot
    const int sw   = (r5 >> 1) & 3;
    const int row0 = blockIdx.x * DBM2;

    // c2 -> LDS (visible before first epilogue at t=15)
    for (int i = tid; i < K_CODES; i += 512) c2_lds[i] = c2s[i];

    // staging lane mapping: 16 rows x 64B per GLD issue, swizzled 16B slot
    const int srow = lane >> 2;
    const int scol = (((lane & 3) ^ ((srow >> 1) & 3))) * 8;  // elements

    float rbv[2][16];
    int   rbi[2][16];
    #pragma unroll
    for (int i = 0; i < 2; ++i)
        #pragma unroll
        for (int r = 0; r < 16; ++r) { rbv[i][r] = 3.4e38f; rbi[i][r] = 0x7fffffff; }

    f32x16 acc[2][2];
    #pragma unroll
    for (int i = 0; i < 2; ++i)
        #pragma unroll
        for (int j = 0; j < 2; ++j) acc[i][j] = (f32x16)0.f;

    // each wave issues EXACTLY 6 GLDs per stage (vmcnt counting relies on it)
    auto stage = [&](int t, int b) {
        const int col0 = (t >> 4) * DBNC;
        const int kk = (t & 15) * DBK;
        GLD(zeh + (size_t)(row0 + w * 16 + srow) * C_DIM + kk + scol,
            &sA[b][0][(w * 16) * DBK]);
        GLD(zel + (size_t)(row0 + w * 16 + srow) * C_DIM + kk + scol,
            &sA[b][1][(w * 16) * DBK]);
        #pragma unroll
        for (int u = 0; u < 2; ++u) {
            const int rB = w * 32 + u * 16;
            GLD(cbh + (size_t)(col0 + rB + srow) * C_DIM + kk + scol,
                &sB[b][0][rB * DBK]);
            GLD(cbl + (size_t)(col0 + rB + srow) * C_DIM + kk + scol,
                &sB[b][1][rB * DBK]);
        }
    };

    __syncthreads();          // drain c2 LDS writes before pipeline starts
    stage(0, 0);
    stage(1, 1);

    int cur = 0;
    #pragma unroll 1
    for (int t = 0; t < NSTEPS; ++t) {
        if (t == NSTEPS - 1) {
            asm volatile("s_waitcnt vmcnt(0)" ::: "memory");
        } else {
            asm volatile("s_waitcnt vmcnt(6)" ::: "memory");  // stage(t) done
        }
        __builtin_amdgcn_s_barrier();

        bf16x8 ah[2][2], al[2][2], bh[2][2], bl[2][2];   // [tile][kh]
        #pragma unroll
        for (int mt = 0; mt < 2; ++mt) {
            const int row = wr * 64 + mt * 32 + r5;
            #pragma unroll
            for (int kh = 0; kh < 2; ++kh) {
                const int off = row * DBK + (((kh * 2 + ksl) ^ sw) * 8);
                ah[mt][kh] = *(const bf16x8*)&sA[cur][0][off];
                al[mt][kh] = *(const bf16x8*)&sA[cur][1][off];
            }
        }
        #pragma unroll
        for (int nt = 0; nt < 2; ++nt) {
            const int row = wc * 64 + nt * 32 + r5;
            #pragma unroll
            for (int kh = 0; kh < 2; ++kh) {
                const int off = row * DBK + (((kh * 2 + ksl) ^ sw) * 8);
                bh[nt][kh] = *(const bf16x8*)&sB[cur][0][off];
                bl[nt][kh] = *(const bf16x8*)&sB[cur][1][off];
            }
        }

        if (t < NSTEPS - 2) {
            int nxt = cur + 2; if (nxt > 2) nxt -= 3;
            stage(t + 2, nxt);        // 6 loads fly across next barriers
        }

        __builtin_amdgcn_s_setprio(1);
        #pragma unroll
        for (int kh = 0; kh < 2; ++kh)          // pass 1: hh
            #pragma unroll
            for (int mt = 0; mt < 2; ++mt)
                #pragma unroll
                for (int nt = 0; nt < 2; ++nt)
                    acc[mt][nt] = __builtin_amdgcn_mfma_f32_32x32x16_bf16(
                        ah[mt][kh], bh[nt][kh], acc[mt][nt], 0, 0, 0);
        #pragma unroll
        for (int kh = 0; kh < 2; ++kh)          // pass 2: hl
            #pragma unroll
            for (int mt = 0; mt < 2; ++mt)
                #pragma unroll
                for (int nt = 0; nt < 2; ++nt)
                    acc[mt][nt] = __builtin_amdgcn_mfma_f32_32x32x16_bf16(
                        ah[mt][kh], bl[nt][kh], acc[mt][nt], 0, 0, 0);
        #pragma unroll
        for (int kh = 0; kh < 2; ++kh)          // pass 3: lh
            #pragma unroll
            for (int mt = 0; mt < 2; ++mt)
                #pragma unroll
                for (int nt = 0; nt < 2; ++nt)
                    acc[mt][nt] = __builtin_amdgcn_mfma_f32_32x32x16_bf16(
                        al[mt][kh], bh[nt][kh], acc[mt][nt], 0, 0, 0);
        __builtin_amdgcn_s_setprio(0);

        if ((t & 15) == 15) {
            // chunk epilogue: d = c2 - 2*dot; codes ascend -> strict < = first
            const int col0 = (t >> 4) * DBNC;
            #pragma unroll
            for (int nt = 0; nt < 2; ++nt) {
                const int code = col0 + wc * 64 + nt * 32 + r5;
                const float c2v = c2_lds[code];
                #pragma unroll
                for (int mt = 0; mt < 2; ++mt)
                    #pragma unroll
                    for (int r = 0; r < 16; ++r) {
                        float d = fmaf(-2.f, acc[mt][nt][r], c2v);
                        if (d < rbv[mt][r]) { rbv[mt][r] = d; rbi[mt][r] = code; }
                    }
            }
            #pragma unroll
            for (int i = 0; i < 2; ++i)
                #pragma unroll
                for (int j = 0; j < 2; ++j) acc[i][j] = (f32x16)0.f;
        }

        cur = (cur == 2) ? 0 : cur + 1;
    }

    // reduce across the 32 lanes of each half (halves own disjoint row sets)
    #pragma unroll
    for (int off = 1; off < 32; off <<= 1) {
        #pragma unroll
        for (int mt = 0; mt < 2; ++mt)
            #pragma unroll
            for (int r = 0; r < 16; ++r) {
                float ov = __shfl_xor(rbv[mt][r], off);
                int   oi = __shfl_xor(rbi[mt][r], off);
                if (ov < rbv[mt][r] || (ov == rbv[mt][r] && oi < rbi[mt][r])) {
                    rbv[mt][r] = ov; rbi[mt][r] = oi;
                }
            }
    }

    __syncthreads();   // full drain; safe to overlay reduce scratch on sA
    float (*s_v)[4] = (float (*)[4])&sA[0][0][0];
    int   (*s_i)[4] = (int (*)[4])((char*)&sA[0][0][0] + DBM2 * 4 * 4);
    if (r5 == 0) {
        #pragma unroll
        for (int mt = 0; mt < 2; ++mt)
            #pragma unroll
            for (int r = 0; r < 16; ++r) {
                const int lrow = wr * 64 + mt * 32 + (r & 3) + 8 * (r >> 2) + 4 * ksl;
                s_v[lrow][wc] = rbv[mt][r];
                s_i[lrow][wc] = rbi[mt][r];
            }
    }
    __syncthreads();
    if (tid < DBM2) {
        float bv = s_v[tid][0]; int bi = s_i[tid][0];
        #pragma unroll
        for (int c = 1; c < 4; ++c) {
            float v = s_v[tid][c]; int i = s_i[tid][c];
            if (v < bv || (v == bv && i < bi)) { bv = v; bi = i; }
        }
        win[tid] = bi;
    }
    __syncthreads();

    // ---- fused residual update: wave w handles rows w*16 .. w*16+15 ----
    // q gathered from bf16 hi/lo codebook (L2-hot); q~ = qh+ql ~ fp32 q.
    const int lane8 = lane * 8;
    float ssum = 0.f;
    #pragma unroll 1
    for (int j = 0; j < 16; ++j) {
        const int lrow = w * 16 + j;
        const size_t base = (size_t)(row0 + lrow) * C_DIM + lane8;
        const int bi = win[lrow];
        const size_t qoff = (size_t)bi * C_DIM + lane8;
        u16x8 qhv = *(const u16x8*)(cbh + qoff);
        u16x8 qlv = *(const u16x8*)(cbl + qoff);
        float qq[8];
        #pragma unroll
        for (int e = 0; e < 8; ++e) qq[e] = u2f(qhv[e]) + u2f(qlv[e]);

        float v[8];
        if (s == 0) {
            float4 z0 = *(const float4*)(x + base);
            float4 z1 = *(const float4*)(x + base + 4);
            v[0]=z0.x; v[1]=z0.y; v[2]=z0.z; v[3]=z0.w;
            v[4]=z1.x; v[5]=z1.y; v[6]=z1.z; v[7]=z1.w;
        } else {
            u16x8 h = *(const u16x8*)(zeh + base);
            u16x8 l = *(const u16x8*)(zel + base);
            #pragma unroll
            for (int e = 0; e < 8; ++e) v[e] = u2f(h[e]) + u2f(l[e]);
        }

        float rr[8];
        #pragma unroll
        for (int e = 0; e < 8; ++e) rr[e] = v[e] - qq[e];

        if (s < Q_STAGES - 1) {
            u16x8 hh, ll;
            #pragma unroll
            for (int e = 0; e < 8; ++e) {
                hh[e] = bf_hi_u(rr[e]);
                float lo = rr[e] - bf_hi_f(rr[e]);
                ll[e] = bf_hi_u(lo);
            }
            *(u16x8*)(zeh + base) = hh;
            *(u16x8*)(zel + base) = ll;
        } else {
            float4 x0 = *(const float4*)(x + base);
            float4 x1 = *(const float4*)(x + base + 4);
            float4 o0, o1;
            o0.x = x0.x - rr[0]; o0.y = x0.y - rr[1];
            o0.z = x0.z - rr[2]; o0.w = x0.w - rr[3];
            o1.x = x1.x - rr[4]; o1.y = x1.y - rr[5];
            o1.z = x1.z - rr[6]; o1.w = x1.w - rr[7];
            *(float4*)(out + base)     = o0;
            *(float4*)(out + base + 4) = o1;
        }

        #pragma unroll
        for (int e = 0; e < 8; ++e) ssum += rr[e] * rr[e];
    }
    #pragma unroll
    for (int off = 1; off < 64; off <<= 1) ssum += __shfl_xor(ssum, off);
    if (lane == 0) swsum[w] = ssum;
    __syncthreads();
    if (tid == 0) {
        float tot = 0.f;
        #pragma unroll
        for (int i = 0; i < 8; ++i) tot += swsum[i];
        rpart[blockIdx.x] = tot;
    }
}

// ---- one deterministic reduce over all stages -> loss ----
__global__ __launch_bounds__(256) void finalize_kernel(
    const float* __restrict__ rpart, float* __restrict__ out_loss)
{
    __shared__ float sm[256];
    const int t = threadIdx.x;
    float v = 0.f;
    #pragma unroll
    for (int s = 0; s < Q_STAGES; ++s) v += rpart[s * 256 + t];
    sm[t] = v;
    __syncthreads();
    for (int w2 = 128; w2 > 0; w2 >>= 1) {
        if (t < w2) sm[t] += sm[t + w2];
        __syncthreads();
    }
    if (t == 0) out_loss[0] = 2.75f * sm[0] / (float)((size_t)N_ROWS * C_DIM);
}

extern "C" void kernel_launch(void* const* d_in, const int* in_sizes, int n_in,
                              void* d_out, int out_size, void* d_ws, size_t ws_size,
                              hipStream_t stream)
{
    const float* x   = (const float*)d_in[0];   // [N, C]
    const float* cbs = (const float*)d_in[1];   // [Q, K, C]
    float* out = (float*)d_out;                 // [N*C] quant_sum, then 1 loss
    char* ws = (char*)d_ws;

    unsigned short* zeh = (unsigned short*)(ws + ZEH_OFF);
    unsigned short* zel = (unsigned short*)(ws + ZEL_OFF);
    unsigned short* cbh = (unsigned short*)(ws + CBH_OFF);
    unsigned short* cbl = (unsigned short*)(ws + CBL_OFF);
    float* c2    = (float*)(ws + C2_OFF);
    float* rpart = (float*)(ws + RPT_OFF);

    // prologue: x -> hi/lo; stage-0 codebook -> hi/lo; all codebook norms
    split_kernel<<<(N_ROWS * C_DIM / 4 + 255) / 256, 256, 0, stream>>>(
        x, zeh, zel, N_ROWS * C_DIM / 4);
    split_kernel<<<(K_CODES * C_DIM / 4 + 255) / 256, 256, 0, stream>>>(
        cbs, cbh, cbl, K_CODES * C_DIM / 4);
    rowsq_kernel<<<(Q_STAGES * K_CODES * 64) / 256, 256, 0, stream>>>(
        cbs, c2, Q_STAGES * K_CODES);

    for (int s = 0; s < Q_STAGES; ++s) {
        dist_fused_kernel<<<N_ROWS / DBM2, 512, 0, stream>>>(
            s, x, zeh, zel, cbh, cbl, c2 + (size_t)s * K_CODES,
            out, rpart + s * 256);
        if (s < Q_STAGES - 1) {
            const float* cbn = cbs + (size_t)(s + 1) * K_CODES * C_DIM;
            split_kernel<<<(K_CODES * C_DIM / 4 + 255) / 256, 256, 0, stream>>>(
                cbn, cbh, cbl, K_CODES * C_DIM / 4);
        }
    }
    finalize_kernel<<<1, 256, 0, stream>>>(rpart, out + (size_t)N_ROWS * C_DIM);
}

// Round 15
// 963.275 us; speedup vs baseline: 1.1743x; 1.1743x over previous
//
#include <hip/hip_runtime.h>

#define N_ROWS 32768
#define C_DIM  512
#define K_CODES 1024
#define Q_STAGES 8

typedef __attribute__((ext_vector_type(8))) short bf16x8;      // 8 bf16 (4 VGPR)
typedef __attribute__((ext_vector_type(4))) float f32x4;       // MFMA acc
typedef __attribute__((ext_vector_type(4))) unsigned short u16x4;
typedef __attribute__((ext_vector_type(8))) unsigned short u16x8;

// workspace layout (bytes) — total <= proven 69.37MB budget
#define ZEH_OFF 0ull          // [N][C] ushort (bf16 hi)  33,554,432
#define ZEL_OFF 33554432ull   // [N][C] ushort (bf16 lo)  33,554,432
#define CBH_OFF 67108864ull   // [K][C] ushort, current stage  1,048,576
#define CBL_OFF 68157440ull   // [K][C] ushort               1,048,576
#define C2_OFF  69206016ull   // [Q][K] float                    32,768
#define RPT_OFF 69238784ull   // [Q][256] float                   8,192

#define GLD(gp, lp) __builtin_amdgcn_global_load_lds( \
    (const __attribute__((address_space(1))) void*)(gp), \
    (__attribute__((address_space(3))) void*)(lp), 16, 0, 0)

__device__ __forceinline__ float bf_hi_f(float f) {
    return __uint_as_float(__float_as_uint(f) & 0xFFFF0000u);
}
__device__ __forceinline__ unsigned short bf_hi_u(float f) {
    return (unsigned short)(__float_as_uint(f) >> 16);
}
__device__ __forceinline__ float u2f(unsigned short u) {
    return __uint_as_float(((unsigned int)u) << 16);
}

__device__ __forceinline__ void split4(const float* __restrict__ src,
    unsigned short* __restrict__ h, unsigned short* __restrict__ l, int i)
{
    float4 v = *(const float4*)(src + (size_t)i * 4);
    u16x4 hv, lv;
    float f, hf;
    f = v.x; hv[0] = bf_hi_u(f); hf = bf_hi_f(f); lv[0] = bf_hi_u(f - hf);
    f = v.y; hv[1] = bf_hi_u(f); hf = bf_hi_f(f); lv[1] = bf_hi_u(f - hf);
    f = v.z; hv[2] = bf_hi_u(f); hf = bf_hi_f(f); lv[2] = bf_hi_u(f - hf);
    f = v.w; hv[3] = bf_hi_u(f); hf = bf_hi_f(f); lv[3] = bf_hi_u(f - hf);
    *(u16x4*)(h + (size_t)i * 4) = hv;
    *(u16x4*)(l + (size_t)i * 4) = lv;
}

// ---- per-stage codebook split (launched between dist stages) ----
__global__ __launch_bounds__(256) void split_kernel(
    const float* __restrict__ src, unsigned short* __restrict__ h,
    unsigned short* __restrict__ l, int n4)
{
    int i = blockIdx.x * 256 + threadIdx.x;
    if (i >= n4) return;
    split4(src, h, l, i);
}

// ---- fused prologue: x split | cb0 split | all codebook norms ----
// blocks [0,16384): x -> zeh/zel; [16384,16896): cb0 -> cbh/cbl;
// [16896,18944): rowsq of all Q*K codebook rows -> c2.
__global__ __launch_bounds__(256) void prologue_kernel(
    const float* __restrict__ x, const float* __restrict__ cbs,
    unsigned short* __restrict__ zeh, unsigned short* __restrict__ zel,
    unsigned short* __restrict__ cbh, unsigned short* __restrict__ cbl,
    float* __restrict__ c2)
{
    const int b = blockIdx.x;
    if (b < 16384) {
        split4(x, zeh, zel, b * 256 + threadIdx.x);
    } else if (b < 16896) {
        split4(cbs, cbh, cbl, (b - 16384) * 256 + threadIdx.x);
    } else {
        const int wave = (b - 16896) * 4 + (threadIdx.x >> 6);
        const int lane = threadIdx.x & 63;
        const float* p = cbs + (size_t)wave * C_DIM + lane * 8;
        float4 a = *(const float4*)p;
        float4 bb = *(const float4*)(p + 4);
        float s = a.x*a.x + a.y*a.y + a.z*a.z + a.w*a.w
                + bb.x*bb.x + bb.y*bb.y + bb.z*bb.z + bb.w*bb.w;
        #pragma unroll
        for (int off = 1; off < 64; off <<= 1) s += __shfl_xor(s, off);
        if (lane == 0) c2[wave] = s;
    }
}

// ---- MFMA distance + argmin + FUSED residual update (R12-proven) ----
// Main loop: R7 schedule (97.5us proven): 128 rows x 1024 codes, 8 waves
// (2Mx4N), 64x64 wave tile, 16x16x32 bf16 MFMA, 3 passes (hh,hl,lh),
// triple-buffer, depth-2 prefetch, counted vmcnt(6), 1 barrier/iter.
// Epilogue: per-row winner -> fp32 codebook gather -> residual -> hi/lo
// write (stage<7) or quant_sum = x - residual (stage 7) -> loss partial.
#define DBM2 128
#define DBNC 256
#define DBK 32
#define NSTEPS 64  // 4 chunks * 16 K-steps

__global__ __launch_bounds__(512, 2) void dist_fused_kernel(
    const int s, const float* __restrict__ x,
    unsigned short* __restrict__ zeh, unsigned short* __restrict__ zel,
    const unsigned short* __restrict__ cbh, const unsigned short* __restrict__ cbl,
    const float* __restrict__ cbf, const float* __restrict__ c2s,
    float* __restrict__ out, float* __restrict__ rpart)
{
    __shared__ unsigned short sA[3][2][DBM2 * DBK];   // 48 KiB
    __shared__ unsigned short sB[3][2][DBNC * DBK];   // 96 KiB
    __shared__ float c2_lds[K_CODES];                 // 4 KiB
    __shared__ int   win[DBM2];                       // 512 B
    __shared__ float swsum[8];                        // 32 B

    const int tid  = threadIdx.x;
    const int lane = tid & 63;
    const int w    = tid >> 6;     // wave 0..7
    const int wr   = w >> 2;       // 0..1 (M)
    const int wc   = w & 3;        // 0..3 (N)
    const int lr   = lane & 15;    // frag row/col
    const int kg   = lane >> 4;    // frag k-group
    const int row0 = blockIdx.x * DBM2;

    // c2 -> LDS (visible before first epilogue at t=15)
    for (int i = tid; i < K_CODES; i += 512) c2_lds[i] = c2s[i];

    // staging lane mapping: 16 rows x 64B per GLD issue, swizzled 16B slot
    const int srow = lane >> 2;
    const int scol = (((lane & 3) ^ ((srow >> 1) & 3))) * 8;  // elements
    const int aslot = (kg ^ ((lr >> 1) & 3)) * 8;             // read-side

    float rbv[4][4];
    int   rbi[4][4];
    #pragma unroll
    for (int i = 0; i < 4; ++i)
        #pragma unroll
        for (int r = 0; r < 4; ++r) { rbv[i][r] = 3.4e38f; rbi[i][r] = 0x7fffffff; }

    f32x4 acc[4][4];
    #pragma unroll
    for (int i = 0; i < 4; ++i)
        #pragma unroll
        for (int j = 0; j < 4; ++j) acc[i][j] = (f32x4)0.f;

    // each wave issues EXACTLY 6 GLDs per stage (vmcnt counting relies on it)
    auto stage = [&](int t, int b) {
        const int col0 = (t >> 4) * DBNC;
        const int kk = (t & 15) * DBK;
        GLD(zeh + (size_t)(row0 + w * 16 + srow) * C_DIM + kk + scol,
            &sA[b][0][(w * 16) * DBK]);
        GLD(zel + (size_t)(row0 + w * 16 + srow) * C_DIM + kk + scol,
            &sA[b][1][(w * 16) * DBK]);
        #pragma unroll
        for (int u = 0; u < 2; ++u) {
            const int rB = w * 32 + u * 16;
            GLD(cbh + (size_t)(col0 + rB + srow) * C_DIM + kk + scol,
                &sB[b][0][rB * DBK]);
            GLD(cbl + (size_t)(col0 + rB + srow) * C_DIM + kk + scol,
                &sB[b][1][rB * DBK]);
        }
    };

    __syncthreads();          // drain c2 LDS writes before pipeline starts
    stage(0, 0);
    stage(1, 1);

    int cur = 0;
    #pragma unroll 1
    for (int t = 0; t < NSTEPS; ++t) {
        if (t == NSTEPS - 1) {
            asm volatile("s_waitcnt vmcnt(0)" ::: "memory");
        } else {
            asm volatile("s_waitcnt vmcnt(6)" ::: "memory");  // stage(t) done
        }
        __builtin_amdgcn_s_barrier();

        bf16x8 ah[4], al[4], bh[4], bl[4];
        #pragma unroll
        for (int mi = 0; mi < 4; ++mi) {
            const int rowoff = (wr * 64 + mi * 16 + lr) * DBK + aslot;
            ah[mi] = *(const bf16x8*)&sA[cur][0][rowoff];
            al[mi] = *(const bf16x8*)&sA[cur][1][rowoff];
        }
        #pragma unroll
        for (int ni = 0; ni < 4; ++ni) {
            const int rowoff = (wc * 64 + ni * 16 + lr) * DBK + aslot;
            bh[ni] = *(const bf16x8*)&sB[cur][0][rowoff];
            bl[ni] = *(const bf16x8*)&sB[cur][1][rowoff];
        }

        if (t < NSTEPS - 2) {
            int nxt = cur + 2; if (nxt > 2) nxt -= 3;
            stage(t + 2, nxt);        // 6 loads fly across next barriers
        }

        __builtin_amdgcn_s_setprio(1);
        #pragma unroll
        for (int mi = 0; mi < 4; ++mi)
            #pragma unroll
            for (int ni = 0; ni < 4; ++ni)
                acc[mi][ni] = __builtin_amdgcn_mfma_f32_16x16x32_bf16(
                    ah[mi], bh[ni], acc[mi][ni], 0, 0, 0);
        #pragma unroll
        for (int mi = 0; mi < 4; ++mi)
            #pragma unroll
            for (int ni = 0; ni < 4; ++ni)
                acc[mi][ni] = __builtin_amdgcn_mfma_f32_16x16x32_bf16(
                    ah[mi], bl[ni], acc[mi][ni], 0, 0, 0);
        #pragma unroll
        for (int mi = 0; mi < 4; ++mi)
            #pragma unroll
            for (int ni = 0; ni < 4; ++ni)
                acc[mi][ni] = __builtin_amdgcn_mfma_f32_16x16x32_bf16(
                    al[mi], bh[ni], acc[mi][ni], 0, 0, 0);
        __builtin_amdgcn_s_setprio(0);

        if ((t & 15) == 15) {
            // chunk epilogue: d = c2 - 2*dot; codes ascend -> strict < = first
            const int col0 = (t >> 4) * DBNC;
            #pragma unroll
            for (int ni = 0; ni < 4; ++ni) {
                const int code = col0 + wc * 64 + ni * 16 + lr;
                const float c2v = c2_lds[code];
                #pragma unroll
                for (int mi = 0; mi < 4; ++mi)
                    #pragma unroll
                    for (int r = 0; r < 4; ++r) {
                        float d = fmaf(-2.f, acc[mi][ni][r], c2v);
                        if (d < rbv[mi][r]) { rbv[mi][r] = d; rbi[mi][r] = code; }
                    }
            }
            #pragma unroll
            for (int i = 0; i < 4; ++i)
                #pragma unroll
                for (int j = 0; j < 4; ++j) acc[i][j] = (f32x4)0.f;
        }

        cur = (cur == 2) ? 0 : cur + 1;
    }

    // reduce across the 16 lanes (lr) sharing each row
    #pragma unroll
    for (int off = 1; off < 16; off <<= 1) {
        #pragma unroll
        for (int mi = 0; mi < 4; ++mi)
            #pragma unroll
            for (int r = 0; r < 4; ++r) {
                float ov = __shfl_xor(rbv[mi][r], off);
                int   oi = __shfl_xor(rbi[mi][r], off);
                if (ov < rbv[mi][r] || (ov == rbv[mi][r] && oi < rbi[mi][r])) {
                    rbv[mi][r] = ov; rbi[mi][r] = oi;
                }
            }
    }

    __syncthreads();   // full drain; safe to overlay reduce scratch on sA
    float (*s_v)[4] = (float (*)[4])&sA[0][0][0];
    int   (*s_i)[4] = (int (*)[4])((char*)&sA[0][0][0] + DBM2 * 4 * 4);
    if (lr == 0) {
        #pragma unroll
        for (int mi = 0; mi < 4; ++mi)
            #pragma unroll
            for (int r = 0; r < 4; ++r) {
                int lrow = wr * 64 + mi * 16 + kg * 4 + r;
                s_v[lrow][wc] = rbv[mi][r];
                s_i[lrow][wc] = rbi[mi][r];
            }
    }
    __syncthreads();
    if (tid < DBM2) {
        float bv = s_v[tid][0]; int bi = s_i[tid][0];
        #pragma unroll
        for (int c = 1; c < 4; ++c) {
            float v = s_v[tid][c]; int i = s_i[tid][c];
            if (v < bv || (v == bv && i < bi)) { bv = v; bi = i; }
        }
        win[tid] = bi;
    }
    __syncthreads();

    // ---- fused residual update: wave w handles rows w*16 .. w*16+15 ----
    const int lane8 = lane * 8;
    float ssum = 0.f;
    #pragma unroll 1
    for (int j = 0; j < 16; ++j) {
        const int lrow = w * 16 + j;
        const size_t base = (size_t)(row0 + lrow) * C_DIM + lane8;
        const int bi = win[lrow];
        const float* q = cbf + (size_t)bi * C_DIM + lane8;
        float4 q0 = *(const float4*)q;
        float4 q1 = *(const float4*)(q + 4);
        float qq[8] = {q0.x, q0.y, q0.z, q0.w, q1.x, q1.y, q1.z, q1.w};

        float v[8];
        if (s == 0) {
            float4 z0 = *(const float4*)(x + base);
            float4 z1 = *(const float4*)(x + base + 4);
            v[0]=z0.x; v[1]=z0.y; v[2]=z0.z; v[3]=z0.w;
            v[4]=z1.x; v[5]=z1.y; v[6]=z1.z; v[7]=z1.w;
        } else {
            u16x8 h = *(const u16x8*)(zeh + base);
            u16x8 l = *(const u16x8*)(zel + base);
            #pragma unroll
            for (int e = 0; e < 8; ++e) v[e] = u2f(h[e]) + u2f(l[e]);
        }

        float rr[8];
        #pragma unroll
        for (int e = 0; e < 8; ++e) rr[e] = v[e] - qq[e];

        if (s < Q_STAGES - 1) {
            u16x8 hh, ll;
            #pragma unroll
            for (int e = 0; e < 8; ++e) {
                hh[e] = bf_hi_u(rr[e]);
                float lo = rr[e] - bf_hi_f(rr[e]);
                ll[e] = bf_hi_u(lo);
            }
            *(u16x8*)(zeh + base) = hh;
            *(u16x8*)(zel + base) = ll;
        } else {
            float4 x0 = *(const float4*)(x + base);
            float4 x1 = *(const float4*)(x + base + 4);
            float4 o0, o1;
            o0.x = x0.x - rr[0]; o0.y = x0.y - rr[1];
            o0.z = x0.z - rr[2]; o0.w = x0.w - rr[3];
            o1.x = x1.x - rr[4]; o1.y = x1.y - rr[5];
            o1.z = x1.z - rr[6]; o1.w = x1.w - rr[7];
            *(float4*)(out + base)     = o0;
            *(float4*)(out + base + 4) = o1;
        }

        #pragma unroll
        for (int e = 0; e < 8; ++e) ssum += rr[e] * rr[e];
    }
    #pragma unroll
    for (int off = 1; off < 64; off <<= 1) ssum += __shfl_xor(ssum, off);
    if (lane == 0) swsum[w] = ssum;
    __syncthreads();
    if (tid == 0) {
        float tot = 0.f;
        #pragma unroll
        for (int i = 0; i < 8; ++i) tot += swsum[i];
        rpart[blockIdx.x] = tot;
    }
}

// ---- one deterministic reduce over all stages -> loss ----
__global__ __launch_bounds__(256) void finalize_kernel(
    const float* __restrict__ rpart, float* __restrict__ out_loss)
{
    __shared__ float sm[256];
    const int t = threadIdx.x;
    float v = 0.f;
    #pragma unroll
    for (int s = 0; s < Q_STAGES; ++s) v += rpart[s * 256 + t];
    sm[t] = v;
    __syncthreads();
    for (int w2 = 128; w2 > 0; w2 >>= 1) {
        if (t < w2) sm[t] += sm[t + w2];
        __syncthreads();
    }
    if (t == 0) out_loss[0] = 2.75f * sm[0] / (float)((size_t)N_ROWS * C_DIM);
}

extern "C" void kernel_launch(void* const* d_in, const int* in_sizes, int n_in,
                              void* d_out, int out_size, void* d_ws, size_t ws_size,
                              hipStream_t stream)
{
    const float* x   = (const float*)d_in[0];   // [N, C]
    const float* cbs = (const float*)d_in[1];   // [Q, K, C]
    float* out = (float*)d_out;                 // [N*C] quant_sum, then 1 loss
    char* ws = (char*)d_ws;

    unsigned short* zeh = (unsigned short*)(ws + ZEH_OFF);
    unsigned short* zel = (unsigned short*)(ws + ZEL_OFF);
    unsigned short* cbh = (unsigned short*)(ws + CBH_OFF);
    unsigned short* cbl = (unsigned short*)(ws + CBL_OFF);
    float* c2    = (float*)(ws + C2_OFF);
    float* rpart = (float*)(ws + RPT_OFF);

    // fused prologue: x -> hi/lo | cb0 -> hi/lo | all codebook norms
    prologue_kernel<<<16384 + 512 + 2048, 256, 0, stream>>>(
        x, cbs, zeh, zel, cbh, cbl, c2);

    for (int s = 0; s < Q_STAGES; ++s) {
        const float* cbf = cbs + (size_t)s * K_CODES * C_DIM;
        dist_fused_kernel<<<N_ROWS / DBM2, 512, 0, stream>>>(
            s, x, zeh, zel, cbh, cbl, cbf, c2 + (size_t)s * K_CODES,
            out, rpart + s * 256);
        if (s < Q_STAGES - 1) {
            split_kernel<<<(K_CODES * C_DIM / 4 + 255) / 256, 256, 0, stream>>>(
                cbf + (size_t)K_CODES * C_DIM, cbh, cbl, K_CODES * C_DIM / 4);
        }
    }
    finalize_kernel<<<1, 256, 0, stream>>>(rpart, out + (size_t)N_ROWS * C_DIM);
}